// Round 2
// baseline (922.503 us; speedup 1.0000x reference)
//
#include <hip/hip_runtime.h>

// ---------------- problem dims (fixed by reference) ----------------
constexpr int BNKv = 200, Lv = 128, Dv = 1024, Ov = 1024, Rv = 50;
constexpr int Mv = BNKv * Lv;     // 25600 rows
constexpr int KA = 2048;          // A' phys: [hi(1024) | lo(1024)]  (seg2 remaps to seg0)
constexpr int KP = 3072;          // logical K: [Ah*Bh | Al*Bh | Ah*Bl]
constexpr int NB = 2048;          // fused N: cols 0-1023 = W_in, 1024-2047 = W_self

using u16 = unsigned short;
typedef __bf16 bf16x8 __attribute__((ext_vector_type(8)));
typedef float f32x4 __attribute__((ext_vector_type(4)));

__device__ __forceinline__ u16 f2bf(float x) {
    unsigned int u = __float_as_uint(x);
    u += 0x7fffu + ((u >> 16) & 1u);
    return (u16)(u >> 16);
}
__device__ __forceinline__ float bf2f(u16 h) {
    return __uint_as_float(((unsigned int)h) << 16);
}

// ---------------------------------------------------------------
// K1: rep (M x 1024 f32) -> A' (M x 2048 bf16, [hi|lo]) + gate dots
// ---------------------------------------------------------------
__global__ __launch_bounds__(256) void convert_rep(
    const float* __restrict__ rep,
    const float* __restrict__ wg_in,
    const float* __restrict__ wg_self,
    u16* __restrict__ Ap,
    float* __restrict__ gout_in,
    float* __restrict__ gout_self)
{
    const int m = blockIdx.x;
    const int t = threadIdx.x;
    const float4 x  = *(const float4*)(rep + (size_t)m * Dv + t * 4);
    const float4 wi = *(const float4*)(wg_in + t * 4);
    const float4 wsf= *(const float4*)(wg_self + t * 4);

    float xs[4] = {x.x, x.y, x.z, x.w};
    u16 hb[4], lb[4];
#pragma unroll
    for (int j = 0; j < 4; ++j) {
        u16 h = f2bf(xs[j]);
        hb[j] = h;
        lb[j] = f2bf(xs[j] - bf2f(h));
    }
    u16* rowp = Ap + (size_t)m * KA;
    *(ushort4*)(rowp + t * 4)        = make_ushort4(hb[0], hb[1], hb[2], hb[3]);
    *(ushort4*)(rowp + 1024 + t * 4) = make_ushort4(lb[0], lb[1], lb[2], lb[3]);

    float gi = x.x * wi.x + x.y * wi.y + x.z * wi.z + x.w * wi.w;
    float gs = x.x * wsf.x + x.y * wsf.y + x.z * wsf.z + x.w * wsf.w;
#pragma unroll
    for (int off = 32; off > 0; off >>= 1) {
        gi += __shfl_down(gi, off);
        gs += __shfl_down(gs, off);
    }
    __shared__ float ri[4], rs[4];
    if ((t & 63) == 0) { ri[t >> 6] = gi; rs[t >> 6] = gs; }
    __syncthreads();
    if (t == 0) {
        gout_in[m]   = ri[0] + ri[1] + ri[2] + ri[3];
        gout_self[m] = rs[0] + rs[1] + rs[2] + rs[3];
    }
}

// ---------------------------------------------------------------
// K2: W (1024x1024 f32) -> Bt rows [n][3072] = [Bh|Bh|Bl] transposed.
// Combined Bt[2048][3072]: z=0 -> rows 0-1023 (W_in), z=1 -> rows 1024-2047.
// ---------------------------------------------------------------
__global__ __launch_bounds__(256) void convert_w(
    const float* __restrict__ W0, const float* __restrict__ W1,
    u16* __restrict__ Bt)
{
    const float* W = blockIdx.z ? W1 : W0;
    u16* B = Bt + (size_t)blockIdx.z * 1024 * KP;
    const int kt = blockIdx.x, nt = blockIdx.y;
    __shared__ float tile[64][65];
    const int tid = threadIdx.x;
    const int c = tid & 63, r4 = tid >> 6;
#pragma unroll 4
    for (int it = 0; it < 16; ++it) {
        int kl = it * 4 + r4;
        tile[kl][c] = W[(size_t)(kt * 64 + kl) * Ov + nt * 64 + c];
    }
    __syncthreads();
#pragma unroll 4
    for (int it = 0; it < 16; ++it) {
        int nl = it * 4 + r4;
        float v = tile[c][nl];
        u16 h = f2bf(v);
        u16 lo = f2bf(v - bf2f(h));
        size_t base = (size_t)(nt * 64 + nl) * KP + kt * 64 + c;
        B[base]        = h;
        B[base + 1024] = h;
        B[base + 2048] = lo;
    }
}

// ---------------------------------------------------------------
// K3: fused GEMM  P[25600][2048] = A'[25600][K=3072 logical] x Bt^T
// 128x128 tile, BK=64, 4 waves (2x2), 16x16x32 bf16 MFMA.
// Double-buffered LDS, ONE barrier per K-step (stage -> buf^1 issued
// before ds_read/MFMA on buf; __syncthreads drains vmcnt+lgkm).
// XCD-aware mapping: each XCD owns 25 contiguous M-panels; the 16
// N-tiles of a panel run consecutively on that XCD (A-panel L2 reuse).
// ---------------------------------------------------------------
__global__ __launch_bounds__(256) void gemm_bt(
    const u16* __restrict__ A, const u16* __restrict__ Bt,
    float* __restrict__ P)
{
    __shared__ u16 As[2][128 * 64];
    __shared__ u16 Bs[2][128 * 64];

    const int tid = threadIdx.x;
    const int l = tid & 63;
    const int w = tid >> 6;

    // XCD-aware bijective remap: grid 3200 = 200 mtiles x 16 ntiles
    const int xcd  = blockIdx.x & 7;
    const int slot = blockIdx.x >> 3;          // 0..399 per XCD
    const int mt   = xcd * 25 + (slot >> 4);   // 0..199
    const int nt   = slot & 15;                // 0..15
    const int gm0 = mt * 128;
    const int gn0 = nt * 128;
    const int wm = (w >> 1) * 64;
    const int wn = (w & 1) * 64;

    const int subrow = l >> 3;         // 0..7 within 8-row chunk
    const int kkoff = (l & 7) * 8;     // 8 bf16 = 16B per lane
    const int lrow = l & 15;
    const int lk = (l >> 4) * 8;

    f32x4 acc[4][4];
#pragma unroll
    for (int i = 0; i < 4; ++i)
#pragma unroll
        for (int j = 0; j < 4; ++j) acc[i][j] = (f32x4){0.f, 0.f, 0.f, 0.f};

    constexpr int NT = KP / 64;  // 48 K-steps

    // --- staging: one K-tile (A 128x64 + B 128x64) into buffer p ---
    auto stage = [&](int t, int p) {
        const int kb = t * 64;
        const int ksA = (kb < KA) ? kb : kb - KA;  // seg2 re-reads hi
#pragma unroll
        for (int i = 0; i < 4; ++i) {
            const int chunk = i * 4 + w;  // wave-uniform
            const u16* ga = A + (size_t)(gm0 + chunk * 8 + subrow) * KA + ksA + kkoff;
            __builtin_amdgcn_global_load_lds(
                (const __attribute__((address_space(1))) void*)ga,
                (__attribute__((address_space(3))) void*)(&As[p][chunk * 512]), 16, 0, 0);
            const u16* gb = Bt + (size_t)(gn0 + chunk * 8 + subrow) * KP + kb + kkoff;
            __builtin_amdgcn_global_load_lds(
                (const __attribute__((address_space(1))) void*)gb,
                (__attribute__((address_space(3))) void*)(&Bs[p][chunk * 512]), 16, 0, 0);
        }
    };

    stage(0, 0);
    __syncthreads();   // drains vmcnt(0): buf0 resident for all waves

    int cur = 0;
    for (int t = 0; t < NT; ++t) {
        if (t + 1 < NT) stage(t + 1, cur ^ 1);   // prefetch next tile
#pragma unroll
        for (int ks = 0; ks < 2; ++ks) {
            const int k0 = ks * 32 + lk;
            bf16x8 af[4], bfr[4];
#pragma unroll
            for (int mi = 0; mi < 4; ++mi)
                af[mi] = *(const bf16x8*)&As[cur][(wm + mi * 16 + lrow) * 64 + k0];
#pragma unroll
            for (int ni = 0; ni < 4; ++ni)
                bfr[ni] = *(const bf16x8*)&Bs[cur][(wn + ni * 16 + lrow) * 64 + k0];
#pragma unroll
            for (int mi = 0; mi < 4; ++mi)
#pragma unroll
                for (int ni = 0; ni < 4; ++ni)
                    acc[mi][ni] = __builtin_amdgcn_mfma_f32_16x16x32_bf16(
                        af[mi], bfr[ni], acc[mi][ni], 0, 0, 0);
        }
        __syncthreads();  // waves done with buf[cur]; staged loads landed
        cur ^= 1;
    }

    const int orow = (l >> 4) * 4;   // C/D: row = (lane>>4)*4 + reg
    const int ocol = l & 15;         //      col = lane&15
#pragma unroll
    for (int mi = 0; mi < 4; ++mi)
#pragma unroll
        for (int ni = 0; ni < 4; ++ni) {
            const int col = gn0 + wn + ni * 16 + ocol;
#pragma unroll
            for (int r = 0; r < 4; ++r) {
                const int row = gm0 + wm + mi * 16 + orow + r;
                P[(size_t)row * NB + col] = acc[mi][ni][r];
            }
        }
}

// ---------------------------------------------------------------
// K4: epilogue. One block per output row m:
//   out[m][:] = relu(w0*(P_in[idx[m]][:] + b_in[lab[m]][:]) + w1*P_self[m][:]) 
// with w0 = am*sigmoid(g_in[idx]+b_gate[lab])*mask, w1 = sigmoid(g_self)*mask
// ---------------------------------------------------------------
__global__ __launch_bounds__(256) void epilogue(
    const float* __restrict__ P,
    const float* __restrict__ g_in, const float* __restrict__ g_self,
    const int* __restrict__ arc, const int* __restrict__ lab,
    const float* __restrict__ am_in, const float* __restrict__ am_loop,
    const float* __restrict__ maskBL,
    const float* __restrict__ b_in, const float* __restrict__ b_gate_in,
    float* __restrict__ out)
{
    const int m = blockIdx.x;
    const int t = threadIdx.x;
    __shared__ float sw0, sw1;
    __shared__ int sgidx, slab;
    if (t == 0) {
        const int gidx = arc[2 * m] * Lv + arc[2 * m + 1];
        const int lb = lab[m];
        const float am = am_in[m], lp = am_loop[m], mk = maskBL[m];
        const float gi = g_in[gidx] + b_gate_in[lb];
        const float gs = g_self[m];
        // relu(x)*mask == relu(x*mask) for mask in {0,1}: fold mask in.
        sw0 = am * am * (1.f / (1.f + expf(-gi))) * mk;
        sw1 = lp * lp * (1.f / (1.f + expf(-gs))) * mk;
        sgidx = gidx;
        slab = lb;
    }
    __syncthreads();
    const float w0 = sw0, w1 = sw1;
    const int c = t * 4;
    const float4 pin = *(const float4*)(P + (size_t)sgidx * NB + c);
    const float4 bi  = *(const float4*)(b_in + (size_t)slab * Ov + c);
    const float4 ps  = *(const float4*)(P + (size_t)m * NB + 1024 + c);
    float4 o;
    o.x = fmaxf(w0 * (pin.x + bi.x) + w1 * ps.x, 0.f);
    o.y = fmaxf(w0 * (pin.y + bi.y) + w1 * ps.y, 0.f);
    o.z = fmaxf(w0 * (pin.z + bi.z) + w1 * ps.z, 0.f);
    o.w = fmaxf(w0 * (pin.w + bi.w) + w1 * ps.w, 0.f);
    *(float4*)(out + (size_t)m * Ov + c) = o;
}

// ---------------- workspace layout ----------------
constexpr size_t SZ_A  = (size_t)Mv * KA * 2;          // 104,857,600
constexpr size_t SZ_B  = (size_t)NB * KP * 2;          //  12,582,912
constexpr size_t OFF_A  = 0;
constexpr size_t OFF_B  = OFF_A + SZ_A;
constexpr size_t OFF_GI = OFF_B + SZ_B;
constexpr size_t OFF_GS = OFF_GI + (size_t)Mv * 4;
constexpr size_t OFF_P  = OFF_GS + (size_t)Mv * 4;     // + 209,715,200

extern "C" void kernel_launch(void* const* d_in, const int* in_sizes, int n_in,
                              void* d_out, int out_size, void* d_ws, size_t ws_size,
                              hipStream_t stream) {
    const float* rep       = (const float*)d_in[0];
    const int*   arc       = (const int*)d_in[1];
    const int*   lab       = (const int*)d_in[2];
    const float* am_in     = (const float*)d_in[3];
    const float* am_loop   = (const float*)d_in[4];
    const float* maskBL    = (const float*)d_in[5];
    const float* W_in      = (const float*)d_in[6];
    const float* b_in      = (const float*)d_in[7];
    const float* W_gate_in = (const float*)d_in[8];
    const float* b_gate_in = (const float*)d_in[9];
    const float* W_self    = (const float*)d_in[10];
    const float* W_gate_self = (const float*)d_in[11];
    float* out = (float*)d_out;
    char* ws = (char*)d_ws;

    u16*   Ap  = (u16*)(ws + OFF_A);
    u16*   Bt  = (u16*)(ws + OFF_B);
    float* gIn = (float*)(ws + OFF_GI);
    float* gSf = (float*)(ws + OFF_GS);
    float* P   = (float*)(ws + OFF_P);

    convert_rep<<<Mv, 256, 0, stream>>>(rep, W_gate_in, W_gate_self, Ap, gIn, gSf);
    convert_w<<<dim3(16, 16, 2), 256, 0, stream>>>(W_in, W_self, Bt);

    const int gemm_grid = (Mv / 128) * (NB / 128);  // 3200
    gemm_bt<<<gemm_grid, 256, 0, stream>>>(Ap, Bt, P);

    epilogue<<<Mv, 256, 0, stream>>>(P, gIn, gSf, arc, lab, am_in, am_loop,
                                     maskBL, b_in, b_gate_in, out);
}

// Round 3
// 603.039 us; speedup vs baseline: 1.5298x; 1.5298x over previous
//
#include <hip/hip_runtime.h>

// ---------------- problem dims (fixed by reference) ----------------
constexpr int BNKv = 200, Lv = 128, Dv = 1024, Ov = 1024;
constexpr int Mv = BNKv * Lv;     // 25600 rows
constexpr int KA = 2048;          // A' phys: [hi(1024) | lo(1024)] (seg2 remaps to seg0)
constexpr int KP = 3072;          // logical K: [Ah*Bh | Al*Bh | Ah*Bl]
constexpr int NB = 2048;          // fused N: cols 0-1023 = W_in, 1024-2047 = W_self
constexpr int NT = KP / 64;       // 48 K-tiles of BK=64

using u16 = unsigned short;
typedef __bf16 bf16x8 __attribute__((ext_vector_type(8)));
typedef float f32x4 __attribute__((ext_vector_type(4)));

__device__ __forceinline__ u16 f2bf(float x) {
    unsigned int u = __float_as_uint(x);
    u += 0x7fffu + ((u >> 16) & 1u);
    return (u16)(u >> 16);
}
__device__ __forceinline__ float bf2f(u16 h) {
    return __uint_as_float(((unsigned int)h) << 16);
}

#define MEMBAR() asm volatile("" ::: "memory")
__device__ __forceinline__ void sbar() {
    MEMBAR(); __builtin_amdgcn_s_barrier(); MEMBAR();
}

// LDS bank-conflict swizzle: storage col = logical col ^ ((row&7)<<3).
// Baked into A'/Bt producers; gemm stages linearly and XORs on ds_read.

// ---------------------------------------------------------------
// K1: rep (M x 1024 f32) -> A' (M x 2048 bf16, [hi|lo], swizzled) + gate dots
// ---------------------------------------------------------------
__global__ __launch_bounds__(256) void convert_rep(
    const float* __restrict__ rep,
    const float* __restrict__ wg_in,
    const float* __restrict__ wg_self,
    u16* __restrict__ Ap,
    float* __restrict__ gout_in,
    float* __restrict__ gout_self)
{
    const int m = blockIdx.x;
    const int t = threadIdx.x;
    const float4 x  = *(const float4*)(rep + (size_t)m * Dv + t * 4);
    const float4 wi = *(const float4*)(wg_in + t * 4);
    const float4 wsf= *(const float4*)(wg_self + t * 4);

    float xs[4] = {x.x, x.y, x.z, x.w};
    u16 hb[4], lb[4];
#pragma unroll
    for (int j = 0; j < 4; ++j) {
        u16 h = f2bf(xs[j]);
        hb[j] = h;
        lb[j] = f2bf(xs[j] - bf2f(h));
    }
    u16* rowp = Ap + (size_t)m * KA;
    const int cs = (t * 4) ^ ((m & 7) << 3);   // swizzled store col (bits>=3 only)
    *(ushort4*)(rowp + cs)        = make_ushort4(hb[0], hb[1], hb[2], hb[3]);
    *(ushort4*)(rowp + 1024 + cs) = make_ushort4(lb[0], lb[1], lb[2], lb[3]);

    float gi = x.x * wi.x + x.y * wi.y + x.z * wi.z + x.w * wi.w;
    float gs = x.x * wsf.x + x.y * wsf.y + x.z * wsf.z + x.w * wsf.w;
#pragma unroll
    for (int off = 32; off > 0; off >>= 1) {
        gi += __shfl_down(gi, off);
        gs += __shfl_down(gs, off);
    }
    __shared__ float ri[4], rs[4];
    if ((t & 63) == 0) { ri[t >> 6] = gi; rs[t >> 6] = gs; }
    __syncthreads();
    if (t == 0) {
        gout_in[m]   = ri[0] + ri[1] + ri[2] + ri[3];
        gout_self[m] = rs[0] + rs[1] + rs[2] + rs[3];
    }
}

// ---------------------------------------------------------------
// K2: W (1024x1024 f32) -> Bt rows [n][3072] = [Bh|Bh|Bl], transposed + swizzled
// ---------------------------------------------------------------
__global__ __launch_bounds__(256) void convert_w(
    const float* __restrict__ W0, const float* __restrict__ W1,
    u16* __restrict__ Bt)
{
    const float* W = blockIdx.z ? W1 : W0;
    u16* B = Bt + (size_t)blockIdx.z * 1024 * KP;
    const int kt = blockIdx.x, nt = blockIdx.y;
    __shared__ float tile[64][65];
    const int tid = threadIdx.x;
    const int c = tid & 63, r4 = tid >> 6;
#pragma unroll 4
    for (int it = 0; it < 16; ++it) {
        int kl = it * 4 + r4;
        tile[kl][c] = W[(size_t)(kt * 64 + kl) * Ov + nt * 64 + c];
    }
    __syncthreads();
#pragma unroll 4
    for (int it = 0; it < 16; ++it) {
        int nl = it * 4 + r4;
        float v = tile[c][nl];
        u16 h = f2bf(v);
        u16 lo = f2bf(v - bf2f(h));
        const int n = nt * 64 + nl;
        const int kx = (kt * 64) + (c ^ ((n & 7) << 3));   // swizzled col
        size_t base = (size_t)n * KP;
        B[base + kx]        = h;
        B[base + 1024 + kx] = h;
        B[base + 2048 + kx] = lo;
    }
}

// ---------------------------------------------------------------
// K3: 8-phase 256x256 GEMM  P[25600][2048] = A' x Bt^T (logical K=3072)
// 512 thr = 8 waves (2M x 4N), per-wave 128x64 out, BK=64, LDS 128KB.
// Half-tile staging (128 rows x 64 K = 2 gload_lds/thread), raw s_barrier,
// counted vmcnt(2) once per K-tile, setprio around MFMA clusters.
// Stage schedule (race-analyzed): kt.p0: A1(kt+1), p1: B0(kt+1),
// p2: B1(kt+1) -> buf^1;  p3: A0(kt+2) -> buf (half0 free after p2 barrier).
// ---------------------------------------------------------------
__global__ __launch_bounds__(512) void gemm8p(
    const u16* __restrict__ A, const u16* __restrict__ Bt,
    float* __restrict__ P)
{
    __shared__ u16 As[2][2][128][64];   // [buf][half][row][col]  64KB
    __shared__ u16 Bs[2][2][128][64];   //                         64KB

    const int tid = threadIdx.x;
    const int l = tid & 63;
    const int w = tid >> 6;            // 0..7
    const int wr = w >> 2;             // A half this wave consumes
    const int wc = w & 3;              // N quarter
    const int hc = wc >> 1;            // B half this wave consumes
    const int mt = blockIdx.x >> 3;    // 0..99   (natural map: nt==XCD ->
    const int nt = blockIdx.x & 7;     // 0..7     B panel pinned per-XCD L2)
    const int gm0 = mt * 256, gn0 = nt * 256;
    const int lrow = l & 15;
    const int lk = (l >> 4) * 8;
    const int swz = (lrow & 7) << 3;
    const int c0 = lk ^ swz, c1 = (32 + lk) ^ swz;  // swizzled ds_read cols
    const int srow = w * 8 + (l >> 3); // staging row within 64-row group
    const int scol = (l & 7) * 8;      // staging col (16B)

    auto stageA = [&](int kt, int h, int b) {
        const int kb = kt * 64;
        const int ksA = (kb < KA) ? kb : kb - KA;   // seg2 re-reads hi
#pragma unroll
        for (int r = 0; r < 2; ++r) {
            const u16* g = A + (size_t)(gm0 + h * 128 + r * 64 + srow) * KA + ksA + scol;
            __builtin_amdgcn_global_load_lds(
                (const __attribute__((address_space(1))) void*)g,
                (__attribute__((address_space(3))) void*)(&As[b][h][r * 64 + w * 8][0]),
                16, 0, 0);
        }
    };
    auto stageB = [&](int kt, int h, int b) {
        const int kb = kt * 64;
#pragma unroll
        for (int r = 0; r < 2; ++r) {
            const u16* g = Bt + (size_t)(gn0 + h * 128 + r * 64 + srow) * KP + kb + scol;
            __builtin_amdgcn_global_load_lds(
                (const __attribute__((address_space(1))) void*)g,
                (__attribute__((address_space(3))) void*)(&Bs[b][h][r * 64 + w * 8][0]),
                16, 0, 0);
        }
    };

    f32x4 acc[8][4];
#pragma unroll
    for (int i = 0; i < 8; ++i)
#pragma unroll
        for (int j = 0; j < 4; ++j) acc[i][j] = (f32x4){0.f, 0.f, 0.f, 0.f};

    // prologue: K-tile 0 fully + A0 of K-tile 1; allow A0(1) in flight
    stageA(0, 0, 0); stageA(0, 1, 0); stageB(0, 0, 0); stageB(0, 1, 0);
    stageA(1, 0, 1);
    asm volatile("s_waitcnt vmcnt(2)" ::: "memory");
    sbar();

    bf16x8 aR[4][2];        // current A quadrant (qm=0 then qm=1)
    bf16x8 bQ[2][2][2];     // [qn][nj][ks], both qn held across phases

    for (int kt = 0; kt < NT; ++kt) {
        const int cur = kt & 1, nx = cur ^ 1;
        const bool st1 = (kt + 1 < NT), st2 = (kt + 2 < NT);

        // ---- phase 0: ds A(qm=0) + B(qn=0); stage A1(kt+1); MFMA q(0,0)
#pragma unroll
        for (int mi = 0; mi < 4; ++mi) {
            aR[mi][0] = *(const bf16x8*)&As[cur][wr][mi * 16 + lrow][c0];
            aR[mi][1] = *(const bf16x8*)&As[cur][wr][mi * 16 + lrow][c1];
        }
#pragma unroll
        for (int nj = 0; nj < 2; ++nj) {
            bQ[0][nj][0] = *(const bf16x8*)&Bs[cur][hc][(wc & 1) * 64 + nj * 16 + lrow][c0];
            bQ[0][nj][1] = *(const bf16x8*)&Bs[cur][hc][(wc & 1) * 64 + nj * 16 + lrow][c1];
        }
        if (st1) stageA(kt + 1, 1, nx);
        __builtin_amdgcn_s_setprio(1);
#pragma unroll
        for (int mi = 0; mi < 4; ++mi)
#pragma unroll
            for (int nj = 0; nj < 2; ++nj)
#pragma unroll
                for (int ks = 0; ks < 2; ++ks)
                    acc[mi][nj] = __builtin_amdgcn_mfma_f32_16x16x32_bf16(
                        aR[mi][ks], bQ[0][nj][ks], acc[mi][nj], 0, 0, 0);
        __builtin_amdgcn_s_setprio(0);
        sbar();

        // ---- phase 1: ds B(qn=1); stage B0(kt+1); MFMA q(0,1)
#pragma unroll
        for (int nj = 0; nj < 2; ++nj) {
            bQ[1][nj][0] = *(const bf16x8*)&Bs[cur][hc][(wc & 1) * 64 + 32 + nj * 16 + lrow][c0];
            bQ[1][nj][1] = *(const bf16x8*)&Bs[cur][hc][(wc & 1) * 64 + 32 + nj * 16 + lrow][c1];
        }
        if (st1) stageB(kt + 1, 0, nx);
        __builtin_amdgcn_s_setprio(1);
#pragma unroll
        for (int mi = 0; mi < 4; ++mi)
#pragma unroll
            for (int nj = 0; nj < 2; ++nj)
#pragma unroll
                for (int ks = 0; ks < 2; ++ks)
                    acc[mi][2 + nj] = __builtin_amdgcn_mfma_f32_16x16x32_bf16(
                        aR[mi][ks], bQ[1][nj][ks], acc[mi][2 + nj], 0, 0, 0);
        __builtin_amdgcn_s_setprio(0);
        sbar();

        // ---- phase 2: ds A(qm=1); stage B1(kt+1); MFMA q(1,0)
#pragma unroll
        for (int mi = 0; mi < 4; ++mi) {
            aR[mi][0] = *(const bf16x8*)&As[cur][wr][64 + mi * 16 + lrow][c0];
            aR[mi][1] = *(const bf16x8*)&As[cur][wr][64 + mi * 16 + lrow][c1];
        }
        if (st1) stageB(kt + 1, 1, nx);
        __builtin_amdgcn_s_setprio(1);
#pragma unroll
        for (int mi = 0; mi < 4; ++mi)
#pragma unroll
            for (int nj = 0; nj < 2; ++nj)
#pragma unroll
                for (int ks = 0; ks < 2; ++ks)
                    acc[4 + mi][nj] = __builtin_amdgcn_mfma_f32_16x16x32_bf16(
                        aR[mi][ks], bQ[0][nj][ks], acc[4 + mi][nj], 0, 0, 0);
        __builtin_amdgcn_s_setprio(0);
        sbar();

        // ---- phase 3: stage A0(kt+2) into freed half of cur; MFMA q(1,1);
        //      counted vmcnt (2 = the A0(kt+2) loads), never 0 mid-loop.
        if (st2) stageA(kt + 2, 0, cur);
        __builtin_amdgcn_s_setprio(1);
#pragma unroll
        for (int mi = 0; mi < 4; ++mi)
#pragma unroll
            for (int nj = 0; nj < 2; ++nj)
#pragma unroll
                for (int ks = 0; ks < 2; ++ks)
                    acc[4 + mi][2 + nj] = __builtin_amdgcn_mfma_f32_16x16x32_bf16(
                        aR[mi][ks], bQ[1][nj][ks], acc[4 + mi][2 + nj], 0, 0, 0);
        __builtin_amdgcn_s_setprio(0);
        if (st2) { asm volatile("s_waitcnt vmcnt(2)" ::: "memory"); }
        else     { asm volatile("s_waitcnt vmcnt(0)" ::: "memory"); }
        sbar();
    }

    // epilogue: C/D layout row=(l>>4)*4+reg, col=l&15
    const int orow = (l >> 4) * 4, ocol = l & 15;
#pragma unroll
    for (int mi = 0; mi < 8; ++mi)
#pragma unroll
        for (int nj = 0; nj < 4; ++nj) {
            const int col = gn0 + wc * 64 + nj * 16 + ocol;
#pragma unroll
            for (int r = 0; r < 4; ++r) {
                const int row = gm0 + wr * 128 + mi * 16 + orow + r;
                P[(size_t)row * NB + col] = acc[mi][nj][r];
            }
        }
}

// ---------------------------------------------------------------
// K4: epilogue. out[m][:] = relu(w0*(P_in[idx[m]][:]+b_in[lab[m]][:]) + w1*P_self[m][:])
// ---------------------------------------------------------------
__global__ __launch_bounds__(256) void epilogue(
    const float* __restrict__ P,
    const float* __restrict__ g_in, const float* __restrict__ g_self,
    const int* __restrict__ arc, const int* __restrict__ lab,
    const float* __restrict__ am_in, const float* __restrict__ am_loop,
    const float* __restrict__ maskBL,
    const float* __restrict__ b_in, const float* __restrict__ b_gate_in,
    float* __restrict__ out)
{
    const int m = blockIdx.x;
    const int t = threadIdx.x;
    __shared__ float sw0, sw1;
    __shared__ int sgidx, slab;
    if (t == 0) {
        const int gidx = arc[2 * m] * Lv + arc[2 * m + 1];
        const int lb = lab[m];
        const float am = am_in[m], lp = am_loop[m], mk = maskBL[m];
        const float gi = g_in[gidx] + b_gate_in[lb];
        const float gs = g_self[m];
        sw0 = am * am * (1.f / (1.f + expf(-gi))) * mk;
        sw1 = lp * lp * (1.f / (1.f + expf(-gs))) * mk;
        sgidx = gidx;
        slab = lb;
    }
    __syncthreads();
    const float w0 = sw0, w1 = sw1;
    const int c = t * 4;
    const float4 pin = *(const float4*)(P + (size_t)sgidx * NB + c);
    const float4 bi  = *(const float4*)(b_in + (size_t)slab * Ov + c);
    const float4 ps  = *(const float4*)(P + (size_t)m * NB + 1024 + c);
    float4 o;
    o.x = fmaxf(w0 * (pin.x + bi.x) + w1 * ps.x, 0.f);
    o.y = fmaxf(w0 * (pin.y + bi.y) + w1 * ps.y, 0.f);
    o.z = fmaxf(w0 * (pin.z + bi.z) + w1 * ps.z, 0.f);
    o.w = fmaxf(w0 * (pin.w + bi.w) + w1 * ps.w, 0.f);
    *(float4*)(out + (size_t)m * Ov + c) = o;
}

// ---------------- workspace layout ----------------
constexpr size_t SZ_A  = (size_t)Mv * KA * 2;          // 104,857,600
constexpr size_t SZ_B  = (size_t)NB * KP * 2;          //  12,582,912
constexpr size_t OFF_A  = 0;
constexpr size_t OFF_B  = OFF_A + SZ_A;
constexpr size_t OFF_GI = OFF_B + SZ_B;
constexpr size_t OFF_GS = OFF_GI + (size_t)Mv * 4;
constexpr size_t OFF_P  = OFF_GS + (size_t)Mv * 4;     // + 209,715,200

extern "C" void kernel_launch(void* const* d_in, const int* in_sizes, int n_in,
                              void* d_out, int out_size, void* d_ws, size_t ws_size,
                              hipStream_t stream) {
    const float* rep       = (const float*)d_in[0];
    const int*   arc       = (const int*)d_in[1];
    const int*   lab       = (const int*)d_in[2];
    const float* am_in     = (const float*)d_in[3];
    const float* am_loop   = (const float*)d_in[4];
    const float* maskBL    = (const float*)d_in[5];
    const float* W_in      = (const float*)d_in[6];
    const float* b_in      = (const float*)d_in[7];
    const float* W_gate_in = (const float*)d_in[8];
    const float* b_gate_in = (const float*)d_in[9];
    const float* W_self    = (const float*)d_in[10];
    const float* W_gate_self = (const float*)d_in[11];
    float* out = (float*)d_out;
    char* ws = (char*)d_ws;

    u16*   Ap  = (u16*)(ws + OFF_A);
    u16*   Bt  = (u16*)(ws + OFF_B);
    float* gIn = (float*)(ws + OFF_GI);
    float* gSf = (float*)(ws + OFF_GS);
    float* P   = (float*)(ws + OFF_P);

    convert_rep<<<Mv, 256, 0, stream>>>(rep, W_gate_in, W_gate_self, Ap, gIn, gSf);
    convert_w<<<dim3(16, 16, 2), 256, 0, stream>>>(W_in, W_self, Bt);

    const int gemm_grid = (Mv / 256) * (NB / 256);  // 800
    gemm8p<<<gemm_grid, 512, 0, stream>>>(Ap, Bt, P);

    epilogue<<<Mv, 256, 0, stream>>>(P, gIn, gSf, arc, lab, am_in, am_loop,
                                     maskBL, b_in, b_gate_in, out);
}

// Round 4
// 396.102 us; speedup vs baseline: 2.3290x; 1.5224x over previous
//
#include <hip/hip_runtime.h>

// ---------------- problem dims (fixed by reference) ----------------
constexpr int BNKv = 200, Lv = 128, Dv = 1024, Ov = 1024;
constexpr int Mv = BNKv * Lv;     // 25600 rows
constexpr int KA = 1024;          // 1-term bf16: A' = bf16(rep), K = 1024
constexpr int NB = 2048;          // fused N: cols 0-1023 = W_in, 1024-2047 = W_self
constexpr int NT = KA / 64;       // 16 K-tiles of BK=64

using u16 = unsigned short;
typedef __bf16 bf16x8 __attribute__((ext_vector_type(8)));
typedef float f32x4 __attribute__((ext_vector_type(4)));

__device__ __forceinline__ u16 f2bf(float x) {
    unsigned int u = __float_as_uint(x);
    u += 0x7fffu + ((u >> 16) & 1u);
    return (u16)(u >> 16);
}

#define MEMBAR() asm volatile("" ::: "memory")
__device__ __forceinline__ void sbar() {
    MEMBAR(); __builtin_amdgcn_s_barrier(); MEMBAR();
}

// LDS bank-conflict swizzle: storage col = logical col ^ ((row&7)<<3),
// baked into A'/Bt producers; gemm stages linearly, XORs on ds_read.
// (Verified round 3: SQ_LDS_BANK_CONFLICT == 0.)

// ---------------------------------------------------------------
// K1: rep (M x 1024 f32) -> A' (M x 1024 bf16, swizzled) + gate dots
// ---------------------------------------------------------------
__global__ __launch_bounds__(256) void convert_rep(
    const float* __restrict__ rep,
    const float* __restrict__ wg_in,
    const float* __restrict__ wg_self,
    u16* __restrict__ Ap,
    float* __restrict__ gout_in,
    float* __restrict__ gout_self)
{
    const int m = blockIdx.x;
    const int t = threadIdx.x;
    const float4 x  = *(const float4*)(rep + (size_t)m * Dv + t * 4);
    const float4 wi = *(const float4*)(wg_in + t * 4);
    const float4 wsf= *(const float4*)(wg_self + t * 4);

    ushort4 hv = make_ushort4(f2bf(x.x), f2bf(x.y), f2bf(x.z), f2bf(x.w));
    const int cs = (t * 4) ^ ((m & 7) << 3);   // swizzled store col (bits 3-5)
    *(ushort4*)(Ap + (size_t)m * KA + cs) = hv;

    float gi = x.x * wi.x + x.y * wi.y + x.z * wi.z + x.w * wi.w;
    float gs = x.x * wsf.x + x.y * wsf.y + x.z * wsf.z + x.w * wsf.w;
#pragma unroll
    for (int off = 32; off > 0; off >>= 1) {
        gi += __shfl_down(gi, off);
        gs += __shfl_down(gs, off);
    }
    __shared__ float ri[4], rs[4];
    if ((t & 63) == 0) { ri[t >> 6] = gi; rs[t >> 6] = gs; }
    __syncthreads();
    if (t == 0) {
        gout_in[m]   = ri[0] + ri[1] + ri[2] + ri[3];
        gout_self[m] = rs[0] + rs[1] + rs[2] + rs[3];
    }
}

// ---------------------------------------------------------------
// K2: W (1024x1024 f32) -> Bt[n][1024] bf16, transposed + swizzled.
// Combined Bt[2048][1024]: z=0 -> rows 0-1023 (W_in), z=1 -> W_self.
// ---------------------------------------------------------------
__global__ __launch_bounds__(256) void convert_w(
    const float* __restrict__ W0, const float* __restrict__ W1,
    u16* __restrict__ Bt)
{
    const float* W = blockIdx.z ? W1 : W0;
    u16* B = Bt + (size_t)blockIdx.z * 1024 * KA;
    const int kt = blockIdx.x, nt = blockIdx.y;
    __shared__ float tile[64][65];
    const int tid = threadIdx.x;
    const int c = tid & 63, r4 = tid >> 6;
#pragma unroll 4
    for (int it = 0; it < 16; ++it) {
        int kl = it * 4 + r4;
        tile[kl][c] = W[(size_t)(kt * 64 + kl) * Ov + nt * 64 + c];
    }
    __syncthreads();
#pragma unroll 4
    for (int it = 0; it < 16; ++it) {
        int nl = it * 4 + r4;
        const int n = nt * 64 + nl;
        const int kx = kt * 64 + (c ^ ((n & 7) << 3));   // swizzled col
        B[(size_t)n * KA + kx] = f2bf(tile[c][nl]);
    }
}

// ---------------------------------------------------------------
// K3: 8-phase 256x256 GEMM  P[25600][2048] = A' x Bt^T (K=1024)
// 512 thr = 8 waves (2M x 4N), per-wave 128x64 out, BK=64, LDS 128KB.
// Deep pipeline: during kt, stage kt+2's B halves at p2 (Bs[cur] free
// after p1 barrier) and A halves at p3 (As[cur] free after p2 barrier);
// single counted vmcnt(8) per K-tile (= kt+2's 8 in-flight loads), so
// kt+1's loads get ~6 phases of latency cover. Never vmcnt(0) mid-loop.
// ---------------------------------------------------------------
__global__ __launch_bounds__(512) void gemm8p(
    const u16* __restrict__ A, const u16* __restrict__ Bt,
    float* __restrict__ P)
{
    __shared__ u16 As[2][2][128][64];   // [buf][half][row][col]  64KB
    __shared__ u16 Bs[2][2][128][64];   //                         64KB

    const int tid = threadIdx.x;
    const int l = tid & 63;
    const int w = tid >> 6;            // 0..7
    const int wr = w >> 2;             // A half this wave consumes
    const int wc = w & 3;              // N quarter
    const int hc = wc >> 1;            // B half this wave consumes
    const int mt = blockIdx.x >> 3;    // 0..99  (natural map: nt==XCD ->
    const int nt = blockIdx.x & 7;     // 0..7    B panel pinned in L2;
    const int gm0 = mt * 256, gn0 = nt * 256;  // A served by L3)
    const int lrow = l & 15;
    const int lk = (l >> 4) * 8;
    const int swz = (lrow & 7) << 3;
    const int c0 = lk ^ swz, c1 = (32 + lk) ^ swz;  // swizzled ds_read cols
    const int srow = w * 8 + (l >> 3); // staging row within 64-row group
    const int scol = (l & 7) * 8;      // staging col (16B)

    auto stageA = [&](int kt, int h, int b) {
        const int kb = kt * 64;
#pragma unroll
        for (int r = 0; r < 2; ++r) {
            const u16* g = A + (size_t)(gm0 + h * 128 + r * 64 + srow) * KA + kb + scol;
            __builtin_amdgcn_global_load_lds(
                (const __attribute__((address_space(1))) void*)g,
                (__attribute__((address_space(3))) void*)(&As[b][h][r * 64 + w * 8][0]),
                16, 0, 0);
        }
    };
    auto stageB = [&](int kt, int h, int b) {
        const int kb = kt * 64;
#pragma unroll
        for (int r = 0; r < 2; ++r) {
            const u16* g = Bt + (size_t)(gn0 + h * 128 + r * 64 + srow) * KA + kb + scol;
            __builtin_amdgcn_global_load_lds(
                (const __attribute__((address_space(1))) void*)g,
                (__attribute__((address_space(3))) void*)(&Bs[b][h][r * 64 + w * 8][0]),
                16, 0, 0);
        }
    };

    f32x4 acc[8][4];
#pragma unroll
    for (int i = 0; i < 8; ++i)
#pragma unroll
        for (int j = 0; j < 4; ++j) acc[i][j] = (f32x4){0.f, 0.f, 0.f, 0.f};

    // prologue: fully stage K-tiles 0 and 1 (8+8 loads); wait tile 0 only.
    stageA(0, 0, 0); stageA(0, 1, 0); stageB(0, 0, 0); stageB(0, 1, 0);
    stageA(1, 0, 1); stageA(1, 1, 1); stageB(1, 0, 1); stageB(1, 1, 1);
    asm volatile("s_waitcnt vmcnt(8)" ::: "memory");
    sbar();

    bf16x8 aR[4][2];        // current A quadrant fragments
    bf16x8 bQ[2][2][2];     // [qn][nj][ks], both qn held across phases

    for (int kt = 0; kt < NT; ++kt) {
        const int cur = kt & 1;
        const bool st2 = (kt + 2 < NT);

        // ---- phase 0: ds A(qm=0) + B(qn=0); MFMA q(0,0). pure compute.
#pragma unroll
        for (int mi = 0; mi < 4; ++mi) {
            aR[mi][0] = *(const bf16x8*)&As[cur][wr][mi * 16 + lrow][c0];
            aR[mi][1] = *(const bf16x8*)&As[cur][wr][mi * 16 + lrow][c1];
        }
#pragma unroll
        for (int nj = 0; nj < 2; ++nj) {
            bQ[0][nj][0] = *(const bf16x8*)&Bs[cur][hc][(wc & 1) * 64 + nj * 16 + lrow][c0];
            bQ[0][nj][1] = *(const bf16x8*)&Bs[cur][hc][(wc & 1) * 64 + nj * 16 + lrow][c1];
        }
        __builtin_amdgcn_s_setprio(1);
#pragma unroll
        for (int mi = 0; mi < 4; ++mi)
#pragma unroll
            for (int nj = 0; nj < 2; ++nj)
#pragma unroll
                for (int ks = 0; ks < 2; ++ks)
                    acc[mi][nj] = __builtin_amdgcn_mfma_f32_16x16x32_bf16(
                        aR[mi][ks], bQ[0][nj][ks], acc[mi][nj], 0, 0, 0);
        __builtin_amdgcn_s_setprio(0);
        sbar();

        // ---- phase 1: ds B(qn=1); MFMA q(0,1). After this barrier Bs[cur] free.
#pragma unroll
        for (int nj = 0; nj < 2; ++nj) {
            bQ[1][nj][0] = *(const bf16x8*)&Bs[cur][hc][(wc & 1) * 64 + 32 + nj * 16 + lrow][c0];
            bQ[1][nj][1] = *(const bf16x8*)&Bs[cur][hc][(wc & 1) * 64 + 32 + nj * 16 + lrow][c1];
        }
        __builtin_amdgcn_s_setprio(1);
#pragma unroll
        for (int mi = 0; mi < 4; ++mi)
#pragma unroll
            for (int nj = 0; nj < 2; ++nj)
#pragma unroll
                for (int ks = 0; ks < 2; ++ks)
                    acc[mi][2 + nj] = __builtin_amdgcn_mfma_f32_16x16x32_bf16(
                        aR[mi][ks], bQ[1][nj][ks], acc[mi][2 + nj], 0, 0, 0);
        __builtin_amdgcn_s_setprio(0);
        sbar();

        // ---- phase 2: ds A(qm=1); stage B(kt+2) into freed Bs[cur]; MFMA q(1,0)
#pragma unroll
        for (int mi = 0; mi < 4; ++mi) {
            aR[mi][0] = *(const bf16x8*)&As[cur][wr][64 + mi * 16 + lrow][c0];
            aR[mi][1] = *(const bf16x8*)&As[cur][wr][64 + mi * 16 + lrow][c1];
        }
        if (st2) { stageB(kt + 2, 0, cur); stageB(kt + 2, 1, cur); }
        __builtin_amdgcn_s_setprio(1);
#pragma unroll
        for (int mi = 0; mi < 4; ++mi)
#pragma unroll
            for (int nj = 0; nj < 2; ++nj)
#pragma unroll
                for (int ks = 0; ks < 2; ++ks)
                    acc[4 + mi][nj] = __builtin_amdgcn_mfma_f32_16x16x32_bf16(
                        aR[mi][ks], bQ[0][nj][ks], acc[4 + mi][nj], 0, 0, 0);
        __builtin_amdgcn_s_setprio(0);
        sbar();

        // ---- phase 3: stage A(kt+2) into freed As[cur]; MFMA q(1,1);
        //      counted vmcnt(8) = kt+2's 8 loads stay in flight.
        if (st2) { stageA(kt + 2, 0, cur); stageA(kt + 2, 1, cur); }
        __builtin_amdgcn_s_setprio(1);
#pragma unroll
        for (int mi = 0; mi < 4; ++mi)
#pragma unroll
            for (int nj = 0; nj < 2; ++nj)
#pragma unroll
                for (int ks = 0; ks < 2; ++ks)
                    acc[4 + mi][2 + nj] = __builtin_amdgcn_mfma_f32_16x16x32_bf16(
                        aR[mi][ks], bQ[1][nj][ks], acc[4 + mi][2 + nj], 0, 0, 0);
        __builtin_amdgcn_s_setprio(0);
        if (st2) { asm volatile("s_waitcnt vmcnt(8)" ::: "memory"); }
        else     { asm volatile("s_waitcnt vmcnt(0)" ::: "memory"); }
        sbar();
    }

    // epilogue: C/D layout row=(l>>4)*4+reg, col=l&15
    const int orow = (l >> 4) * 4, ocol = l & 15;
#pragma unroll
    for (int mi = 0; mi < 8; ++mi)
#pragma unroll
        for (int nj = 0; nj < 4; ++nj) {
            const int col = gn0 + wc * 64 + nj * 16 + ocol;
#pragma unroll
            for (int r = 0; r < 4; ++r) {
                const int row = gm0 + wr * 128 + mi * 16 + orow + r;
                P[(size_t)row * NB + col] = acc[mi][nj][r];
            }
        }
}

// ---------------------------------------------------------------
// K4: epilogue. out[m][:] = relu(w0*(P_in[idx[m]][:]+b_in[lab[m]][:]) + w1*P_self[m][:])
// ---------------------------------------------------------------
__global__ __launch_bounds__(256) void epilogue(
    const float* __restrict__ P,
    const float* __restrict__ g_in, const float* __restrict__ g_self,
    const int* __restrict__ arc, const int* __restrict__ lab,
    const float* __restrict__ am_in, const float* __restrict__ am_loop,
    const float* __restrict__ maskBL,
    const float* __restrict__ b_in, const float* __restrict__ b_gate_in,
    float* __restrict__ out)
{
    const int m = blockIdx.x;
    const int t = threadIdx.x;
    __shared__ float sw0, sw1;
    __shared__ int sgidx, slab;
    if (t == 0) {
        const int gidx = arc[2 * m] * Lv + arc[2 * m + 1];
        const int lb = lab[m];
        const float am = am_in[m], lp = am_loop[m], mk = maskBL[m];
        const float gi = g_in[gidx] + b_gate_in[lb];
        const float gs = g_self[m];
        // relu(x)*mask == relu(x*mask) for mask in {0,1}: fold mask in.
        sw0 = am * am * (1.f / (1.f + expf(-gi))) * mk;
        sw1 = lp * lp * (1.f / (1.f + expf(-gs))) * mk;
        sgidx = gidx;
        slab = lb;
    }
    __syncthreads();
    const float w0 = sw0, w1 = sw1;
    const int c = t * 4;
    const float4 pin = *(const float4*)(P + (size_t)sgidx * NB + c);
    const float4 bi  = *(const float4*)(b_in + (size_t)slab * Ov + c);
    const float4 ps  = *(const float4*)(P + (size_t)m * NB + 1024 + c);
    float4 o;
    o.x = fmaxf(w0 * (pin.x + bi.x) + w1 * ps.x, 0.f);
    o.y = fmaxf(w0 * (pin.y + bi.y) + w1 * ps.y, 0.f);
    o.z = fmaxf(w0 * (pin.z + bi.z) + w1 * ps.z, 0.f);
    o.w = fmaxf(w0 * (pin.w + bi.w) + w1 * ps.w, 0.f);
    *(float4*)(out + (size_t)m * Ov + c) = o;
}

// ---------------- workspace layout ----------------
constexpr size_t SZ_A  = (size_t)Mv * KA * 2;          //  52,428,800
constexpr size_t SZ_B  = (size_t)NB * KA * 2;          //   4,194,304
constexpr size_t OFF_A  = 0;
constexpr size_t OFF_B  = OFF_A + SZ_A;
constexpr size_t OFF_GI = OFF_B + SZ_B;
constexpr size_t OFF_GS = OFF_GI + (size_t)Mv * 4;
constexpr size_t OFF_P  = OFF_GS + (size_t)Mv * 4;     // + 209,715,200

extern "C" void kernel_launch(void* const* d_in, const int* in_sizes, int n_in,
                              void* d_out, int out_size, void* d_ws, size_t ws_size,
                              hipStream_t stream) {
    const float* rep       = (const float*)d_in[0];
    const int*   arc       = (const int*)d_in[1];
    const int*   lab       = (const int*)d_in[2];
    const float* am_in     = (const float*)d_in[3];
    const float* am_loop   = (const float*)d_in[4];
    const float* maskBL    = (const float*)d_in[5];
    const float* W_in      = (const float*)d_in[6];
    const float* b_in      = (const float*)d_in[7];
    const float* W_gate_in = (const float*)d_in[8];
    const float* b_gate_in = (const float*)d_in[9];
    const float* W_self    = (const float*)d_in[10];
    const float* W_gate_self = (const float*)d_in[11];
    float* out = (float*)d_out;
    char* ws = (char*)d_ws;

    u16*   Ap  = (u16*)(ws + OFF_A);
    u16*   Bt  = (u16*)(ws + OFF_B);
    float* gIn = (float*)(ws + OFF_GI);
    float* gSf = (float*)(ws + OFF_GS);
    float* P   = (float*)(ws + OFF_P);

    convert_rep<<<Mv, 256, 0, stream>>>(rep, W_gate_in, W_gate_self, Ap, gIn, gSf);
    convert_w<<<dim3(16, 16, 2), 256, 0, stream>>>(W_in, W_self, Bt);

    const int gemm_grid = (Mv / 256) * (NB / 256);  // 800
    gemm8p<<<gemm_grid, 512, 0, stream>>>(Ap, Bt, P);

    epilogue<<<Mv, 256, 0, stream>>>(P, gIn, gSf, arc, lab, am_in, am_loop,
                                     maskBL, b_in, b_gate_in, out);
}

// Round 5
// 362.115 us; speedup vs baseline: 2.5475x; 1.0939x over previous
//
#include <hip/hip_runtime.h>

// ---------------- problem dims (fixed by reference) ----------------
constexpr int BNKv = 200, Lv = 128, Dv = 1024, Ov = 1024;
constexpr int Mv = BNKv * Lv;     // 25600 rows
constexpr int KA = 1024;          // 1-term bf16 K
constexpr int NT = KA / 64;       // 16 K-tiles of BK=64

using u16 = unsigned short;
typedef __bf16 bf16x8 __attribute__((ext_vector_type(8)));
typedef float f32x4 __attribute__((ext_vector_type(4)));

__device__ __forceinline__ u16 f2bf(float x) {
    unsigned int u = __float_as_uint(x);
    u += 0x7fffu + ((u >> 16) & 1u);
    return (u16)(u >> 16);
}

#define MEMBAR() asm volatile("" ::: "memory")
__device__ __forceinline__ void sbar() {
    MEMBAR(); __builtin_amdgcn_s_barrier(); MEMBAR();
}

// LDS bank-conflict swizzle: storage col = logical col ^ ((row&7)<<3),
// baked into A'/Bt producers; gemm stages linearly, XORs on ds_read.
// (Verified round 3/4: SQ_LDS_BANK_CONFLICT == 0.)

// ---------------------------------------------------------------
// K1: rep (M x 1024 f32) -> A' (M x 1024 bf16, swizzled) + gate dots.
// 4 rows per block (one wave per row).
// ---------------------------------------------------------------
__global__ __launch_bounds__(256) void convert_rep(
    const float* __restrict__ rep,
    const float* __restrict__ wg_in,
    const float* __restrict__ wg_self,
    u16* __restrict__ Ap,
    float* __restrict__ gout_in,
    float* __restrict__ gout_self)
{
    const int row = blockIdx.x * 4 + (threadIdx.x >> 6);
    const int l = threadIdx.x & 63;
    const float4* rp  = (const float4*)(rep + (size_t)row * Dv);
    const float4* wip = (const float4*)wg_in;
    const float4* wsp = (const float4*)wg_self;
    u16* ap = Ap + (size_t)row * KA;
    const int sw = (row & 7) << 3;
    float gi = 0.f, gs = 0.f;
#pragma unroll
    for (int j = 0; j < 4; ++j) {
        const int c4 = j * 64 + l;            // float4 index; u16 col = c4*4
        const float4 x  = rp[c4];
        const float4 wi = wip[c4];
        const float4 wf = wsp[c4];
        ushort4 hv = make_ushort4(f2bf(x.x), f2bf(x.y), f2bf(x.z), f2bf(x.w));
        *(ushort4*)(ap + ((c4 * 4) ^ sw)) = hv;   // swizzled store (bits 3-5)
        gi += x.x * wi.x + x.y * wi.y + x.z * wi.z + x.w * wi.w;
        gs += x.x * wf.x + x.y * wf.y + x.z * wf.z + x.w * wf.w;
    }
#pragma unroll
    for (int off = 32; off > 0; off >>= 1) {
        gi += __shfl_down(gi, off);
        gs += __shfl_down(gs, off);
    }
    if (l == 0) { gout_in[row] = gi; gout_self[row] = gs; }
}

// ---------------------------------------------------------------
// K2: W (1024x1024 f32) -> Bt[n][1024] bf16, transposed + swizzled.
// Bt[2048][1024]: z=0 -> rows 0-1023 (W_in), z=1 -> W_self.
// ---------------------------------------------------------------
__global__ __launch_bounds__(256) void convert_w(
    const float* __restrict__ W0, const float* __restrict__ W1,
    u16* __restrict__ Bt)
{
    const float* W = blockIdx.z ? W1 : W0;
    u16* B = Bt + (size_t)blockIdx.z * 1024 * KA;
    const int kt = blockIdx.x, nt = blockIdx.y;
    __shared__ float tile[64][65];
    const int tid = threadIdx.x;
    const int c = tid & 63, r4 = tid >> 6;
#pragma unroll 4
    for (int it = 0; it < 16; ++it) {
        int kl = it * 4 + r4;
        tile[kl][c] = W[(size_t)(kt * 64 + kl) * Ov + nt * 64 + c];
    }
    __syncthreads();
#pragma unroll 4
    for (int it = 0; it < 16; ++it) {
        int nl = it * 4 + r4;
        const int n = nt * 64 + nl;
        const int kx = kt * 64 + (c ^ ((n & 7) << 3));   // swizzled col
        B[(size_t)n * KA + kx] = f2bf(tile[c][nl]);
    }
}

// ---------------------------------------------------------------
// K3: 8-phase 256x256 GEMM over K=1024 (identical pipeline to round 4,
// verified: conflicts 0). N = 1024 per kernel, grid 100 mt x 4 nt = 400.
//  FUSED=false: P_in[m][n] = A'[m] . W_in^T[n]     (plain f32 store)
//  FUSED=true : self-part + full epilogue ->
//     out[m][n] = relu(w0[m]*(P_in[gidx[m]][n] + b_in[lab[m]][n])
//                      + w1[m]*self_acc)
// Per-row gates/idx precomputed into LDS by tid<256 at block start.
// ---------------------------------------------------------------
template <bool FUSED>
__global__ __launch_bounds__(512) void gemm8p(
    const u16* __restrict__ A, const u16* __restrict__ Bt,
    float* __restrict__ OutP,             // !FUSED: P_in; FUSED: out
    const float* __restrict__ Pin,        // FUSED: gather source
    const float* __restrict__ g_in, const float* __restrict__ g_self,
    const int* __restrict__ arc, const int* __restrict__ lab,
    const float* __restrict__ am_in, const float* __restrict__ am_loop,
    const float* __restrict__ maskBL,
    const float* __restrict__ b_in, const float* __restrict__ b_gate_in)
{
    __shared__ u16 As[2][2][128][64];   // [buf][half][row][col]  64KB
    __shared__ u16 Bs[2][2][128][64];   //                         64KB
    __shared__ float w0s[FUSED ? 256 : 1], w1s[FUSED ? 256 : 1];
    __shared__ int  pidx[FUSED ? 256 : 1], plab[FUSED ? 256 : 1];

    const int tid = threadIdx.x;
    const int l = tid & 63;
    const int w = tid >> 6;            // 0..7
    const int wr = w >> 2;             // A half this wave consumes
    const int wc = w & 3;              // N quarter
    const int hc = wc >> 1;            // B half this wave consumes
    const int mt = blockIdx.x >> 2;    // 0..99
    const int nt = blockIdx.x & 3;     // 0..3 (xcd&3 -> B panel L2-pinned)
    const int gm0 = mt * 256, gn0 = nt * 256;
    const int lrow = l & 15;
    const int lk = (l >> 4) * 8;
    const int swz = (lrow & 7) << 3;
    const int c0 = lk ^ swz, c1 = (32 + lk) ^ swz;  // swizzled ds_read cols
    const int srow = w * 8 + (l >> 3); // staging row within 64-row group
    const int scol = (l & 7) * 8;      // staging col (16B)

    if constexpr (FUSED) {
        if (tid < 256) {
            const int m = gm0 + tid;
            const int gidx = arc[2 * m] * Lv + arc[2 * m + 1];
            const int lb = lab[m];
            const float am = am_in[m], lp = am_loop[m], mk = maskBL[m];
            const float gi = g_in[gidx] + b_gate_in[lb];
            const float gs = g_self[m];
            // relu(x)*mask == relu(x*mask) for mask in {0,1}: fold mask in.
            w0s[tid] = am * am * (1.f / (1.f + expf(-gi))) * mk;
            w1s[tid] = lp * lp * (1.f / (1.f + expf(-gs))) * mk;
            pidx[tid] = gidx;
            plab[tid] = lb;
        }
    }

    auto stageA = [&](int kt, int h, int b) {
        const int kb = kt * 64;
#pragma unroll
        for (int r = 0; r < 2; ++r) {
            const u16* g = A + (size_t)(gm0 + h * 128 + r * 64 + srow) * KA + kb + scol;
            __builtin_amdgcn_global_load_lds(
                (const __attribute__((address_space(1))) void*)g,
                (__attribute__((address_space(3))) void*)(&As[b][h][r * 64 + w * 8][0]),
                16, 0, 0);
        }
    };
    auto stageB = [&](int kt, int h, int b) {
        const int kb = kt * 64;
#pragma unroll
        for (int r = 0; r < 2; ++r) {
            const u16* g = Bt + (size_t)(gn0 + h * 128 + r * 64 + srow) * KA + kb + scol;
            __builtin_amdgcn_global_load_lds(
                (const __attribute__((address_space(1))) void*)g,
                (__attribute__((address_space(3))) void*)(&Bs[b][h][r * 64 + w * 8][0]),
                16, 0, 0);
        }
    };

    f32x4 acc[8][4];
#pragma unroll
    for (int i = 0; i < 8; ++i)
#pragma unroll
        for (int j = 0; j < 4; ++j) acc[i][j] = (f32x4){0.f, 0.f, 0.f, 0.f};

    // prologue: fully stage K-tiles 0 and 1; wait tile 0 only.
    stageA(0, 0, 0); stageA(0, 1, 0); stageB(0, 0, 0); stageB(0, 1, 0);
    stageA(1, 0, 1); stageA(1, 1, 1); stageB(1, 0, 1); stageB(1, 1, 1);
    asm volatile("s_waitcnt vmcnt(8)" ::: "memory");
    sbar();

    bf16x8 aR[4][2];        // current A quadrant fragments
    bf16x8 bQ[2][2][2];     // [qn][nj][ks], both qn held across phases

    for (int kt = 0; kt < NT; ++kt) {
        const int cur = kt & 1;
        const bool st2 = (kt + 2 < NT);

        // ---- phase 0: ds A(qm=0) + B(qn=0); MFMA q(0,0). pure compute.
#pragma unroll
        for (int mi = 0; mi < 4; ++mi) {
            aR[mi][0] = *(const bf16x8*)&As[cur][wr][mi * 16 + lrow][c0];
            aR[mi][1] = *(const bf16x8*)&As[cur][wr][mi * 16 + lrow][c1];
        }
#pragma unroll
        for (int nj = 0; nj < 2; ++nj) {
            bQ[0][nj][0] = *(const bf16x8*)&Bs[cur][hc][(wc & 1) * 64 + nj * 16 + lrow][c0];
            bQ[0][nj][1] = *(const bf16x8*)&Bs[cur][hc][(wc & 1) * 64 + nj * 16 + lrow][c1];
        }
        __builtin_amdgcn_s_setprio(1);
#pragma unroll
        for (int mi = 0; mi < 4; ++mi)
#pragma unroll
            for (int nj = 0; nj < 2; ++nj)
#pragma unroll
                for (int ks = 0; ks < 2; ++ks)
                    acc[mi][nj] = __builtin_amdgcn_mfma_f32_16x16x32_bf16(
                        aR[mi][ks], bQ[0][nj][ks], acc[mi][nj], 0, 0, 0);
        __builtin_amdgcn_s_setprio(0);
        sbar();

        // ---- phase 1: ds B(qn=1); MFMA q(0,1). After barrier Bs[cur] free.
#pragma unroll
        for (int nj = 0; nj < 2; ++nj) {
            bQ[1][nj][0] = *(const bf16x8*)&Bs[cur][hc][(wc & 1) * 64 + 32 + nj * 16 + lrow][c0];
            bQ[1][nj][1] = *(const bf16x8*)&Bs[cur][hc][(wc & 1) * 64 + 32 + nj * 16 + lrow][c1];
        }
        __builtin_amdgcn_s_setprio(1);
#pragma unroll
        for (int mi = 0; mi < 4; ++mi)
#pragma unroll
            for (int nj = 0; nj < 2; ++nj)
#pragma unroll
                for (int ks = 0; ks < 2; ++ks)
                    acc[mi][2 + nj] = __builtin_amdgcn_mfma_f32_16x16x32_bf16(
                        aR[mi][ks], bQ[1][nj][ks], acc[mi][2 + nj], 0, 0, 0);
        __builtin_amdgcn_s_setprio(0);
        sbar();

        // ---- phase 2: ds A(qm=1); stage B(kt+2) into freed Bs[cur]; MFMA q(1,0)
#pragma unroll
        for (int mi = 0; mi < 4; ++mi) {
            aR[mi][0] = *(const bf16x8*)&As[cur][wr][64 + mi * 16 + lrow][c0];
            aR[mi][1] = *(const bf16x8*)&As[cur][wr][64 + mi * 16 + lrow][c1];
        }
        if (st2) { stageB(kt + 2, 0, cur); stageB(kt + 2, 1, cur); }
        __builtin_amdgcn_s_setprio(1);
#pragma unroll
        for (int mi = 0; mi < 4; ++mi)
#pragma unroll
            for (int nj = 0; nj < 2; ++nj)
#pragma unroll
                for (int ks = 0; ks < 2; ++ks)
                    acc[4 + mi][nj] = __builtin_amdgcn_mfma_f32_16x16x32_bf16(
                        aR[mi][ks], bQ[0][nj][ks], acc[4 + mi][nj], 0, 0, 0);
        __builtin_amdgcn_s_setprio(0);
        sbar();

        // ---- phase 3: stage A(kt+2) into freed As[cur]; MFMA q(1,1);
        //      counted vmcnt(8) = kt+2's 8 loads stay in flight.
        if (st2) { stageA(kt + 2, 0, cur); stageA(kt + 2, 1, cur); }
        __builtin_amdgcn_s_setprio(1);
#pragma unroll
        for (int mi = 0; mi < 4; ++mi)
#pragma unroll
            for (int nj = 0; nj < 2; ++nj)
#pragma unroll
                for (int ks = 0; ks < 2; ++ks)
                    acc[4 + mi][2 + nj] = __builtin_amdgcn_mfma_f32_16x16x32_bf16(
                        aR[mi][ks], bQ[1][nj][ks], acc[4 + mi][2 + nj], 0, 0, 0);
        __builtin_amdgcn_s_setprio(0);
        if (st2) { asm volatile("s_waitcnt vmcnt(8)" ::: "memory"); }
        else     { asm volatile("s_waitcnt vmcnt(0)" ::: "memory"); }
        sbar();
    }

    // epilogue: C/D layout row=(l>>4)*4+reg, col=l&15
    const int orow = (l >> 4) * 4, ocol = l & 15;
    if constexpr (!FUSED) {
#pragma unroll
        for (int mi = 0; mi < 8; ++mi)
#pragma unroll
            for (int nj = 0; nj < 4; ++nj) {
                const int col = gn0 + wc * 64 + nj * 16 + ocol;
#pragma unroll
                for (int r = 0; r < 4; ++r) {
                    const int row = gm0 + wr * 128 + mi * 16 + orow + r;
                    OutP[(size_t)row * Ov + col] = acc[mi][nj][r];
                }
            }
    } else {
#pragma unroll
        for (int mi = 0; mi < 8; ++mi) {
#pragma unroll
            for (int r = 0; r < 4; ++r) {
                const int rloc = wr * 128 + mi * 16 + orow + r;
                const float w0 = w0s[rloc], w1 = w1s[rloc];
                const size_t prow = (size_t)pidx[rloc] * Ov;
                const size_t brow = (size_t)plab[rloc] * Ov;
                const size_t grow = (size_t)(gm0 + rloc) * Ov;
#pragma unroll
                for (int nj = 0; nj < 4; ++nj) {
                    const int col = gn0 + wc * 64 + nj * 16 + ocol;
                    const float pin = Pin[prow + col] + b_in[brow + col];
                    const float v = w0 * pin + w1 * acc[mi][nj][r];
                    OutP[grow + col] = fmaxf(v, 0.f);
                }
            }
        }
    }
}

// ---------------- workspace layout ----------------
constexpr size_t SZ_A  = (size_t)Mv * KA * 2;          //  52,428,800
constexpr size_t SZ_B  = (size_t)2 * 1024 * KA * 2;    //   4,194,304
constexpr size_t OFF_A  = 0;
constexpr size_t OFF_B  = OFF_A + SZ_A;
constexpr size_t OFF_GI = OFF_B + SZ_B;
constexpr size_t OFF_GS = OFF_GI + (size_t)Mv * 4;
constexpr size_t OFF_P  = OFF_GS + (size_t)Mv * 4;     // + 104,857,600

extern "C" void kernel_launch(void* const* d_in, const int* in_sizes, int n_in,
                              void* d_out, int out_size, void* d_ws, size_t ws_size,
                              hipStream_t stream) {
    const float* rep       = (const float*)d_in[0];
    const int*   arc       = (const int*)d_in[1];
    const int*   lab       = (const int*)d_in[2];
    const float* am_in     = (const float*)d_in[3];
    const float* am_loop   = (const float*)d_in[4];
    const float* maskBL    = (const float*)d_in[5];
    const float* W_in      = (const float*)d_in[6];
    const float* b_in      = (const float*)d_in[7];
    const float* W_gate_in = (const float*)d_in[8];
    const float* b_gate_in = (const float*)d_in[9];
    const float* W_self    = (const float*)d_in[10];
    const float* W_gate_self = (const float*)d_in[11];
    float* out = (float*)d_out;
    char* ws = (char*)d_ws;

    u16*   Ap  = (u16*)(ws + OFF_A);
    u16*   Bt  = (u16*)(ws + OFF_B);           // [0:1024) = W_in^T
    u16*   BtS = Bt + (size_t)1024 * KA;       // [1024:2048) = W_self^T
    float* gIn = (float*)(ws + OFF_GI);
    float* gSf = (float*)(ws + OFF_GS);
    float* Pin = (float*)(ws + OFF_P);

    convert_rep<<<Mv / 4, 256, 0, stream>>>(rep, W_gate_in, W_gate_self, Ap, gIn, gSf);
    convert_w<<<dim3(16, 16, 2), 256, 0, stream>>>(W_in, W_self, Bt);

    const int grid = (Mv / 256) * (1024 / 256);  // 400
    gemm8p<false><<<grid, 512, 0, stream>>>(
        Ap, Bt, Pin, nullptr, nullptr, nullptr, nullptr, nullptr,
        nullptr, nullptr, nullptr, nullptr, nullptr);
    gemm8p<true><<<grid, 512, 0, stream>>>(
        Ap, BtS, out, Pin, gIn, gSf, arc, lab, am_in, am_loop,
        maskBL, b_in, b_gate_in);
}